// Round 4
// baseline (247.454 us; speedup 1.0000x reference)
//
#include <hip/hip_runtime.h>
#include <hip/hip_bf16.h>
#include <stdint.h>

typedef __hip_bfloat16 bf16;
typedef __attribute__((ext_vector_type(8))) short short8;    // 8 bf16 = 4 VGPRs (MFMA A/B frag)
typedef __attribute__((ext_vector_type(16))) float floatx16; // 32x32 MFMA C/D frag

#define AS1(p) ((const __attribute__((address_space(1))) void*)(p))
#define AS3(p) ((__attribute__((address_space(3))) void*)(p))

#define M_DIM 4096
#define H_DIM 1024
#define STAGE 24576          // A 8KB + B 16KB per K-step(32); 3 stages = 72KB -> 2 blocks/CU

// fp32 -> bf16 bits, round-to-nearest-even (inputs are finite)
__device__ __forceinline__ unsigned short f2bf(float f) {
    uint32_t u = __float_as_uint(f);
    uint32_t r = (u + 0x7FFFu + ((u >> 16) & 1u)) >> 16;
    return (unsigned short)r;
}
__device__ __forceinline__ float fast_sigmoid(float v) {
    return 1.0f / (1.0f + __expf(-v));
}
__device__ __forceinline__ float fast_tanh(float v) {
    return 2.0f / (1.0f + __expf(-2.0f * v)) - 1.0f;
}

// ---------------------------------------------------------------------------
// Kernel 1: PACK fp32 -> bf16 chunks, lane-LINEAR (no swizzle: the 32x32x16
// fragment order IS linear lane order).  One chunk = 1 KB = [2 kh][32 rows]
// [8 bf16] = the exact A/B fragment for one 32-row x 16-k tile; lane l reads
// bytes l*16 of the chunk.
// Unified KT: kq in [0,128) spans x-K (kq<64) then h-K (kq>=64), so the GEMM
// walks K with one uniform pointer increment (no phase select).
// Chunk map (32768 chunks x 1KB = 32MB):
//   A (W<16384):  W = (mx*128 + kq)*4 + ch4 ; mx<32 (128-row panel),
//                 ch4<4 (32-row group) ; row = mx*128+ch4*32+r
//   B (W>=16384): W-16384 = (ny*8 + b8)*128 + kq ; ny<16 (64-col panel),
//                 b8 = g*2+nh (gate, 32-col half) ; row = ny*64+nh*32+r
__global__ __launch_bounds__(256)
void pack_bf16(const float* __restrict__ x, const float* __restrict__ h,
               const float* Wxf, const float* Wxi, const float* Wxo, const float* Wxc,
               const float* Whf, const float* Whi, const float* Who, const float* Whc,
               unsigned short* __restrict__ ws)
{
    const int w = threadIdx.x >> 6;
    const int l = threadIdx.x & 63;
    const uint32_t W = blockIdx.x * 4u + (uint32_t)w;   // chunk id [0, 32768)

    const uint32_t r  = (uint32_t)l & 31u;   // row in chunk
    const uint32_t kh = (uint32_t)l >> 5;    // k-subgroup of 8

    const float* src;
    uint32_t row, kq;
    if (W < 16384u) {                    // A-chunks (x / h)
        const uint32_t ch4 = W & 3u;
        kq = (W >> 2) & 127u;
        const uint32_t mx = W >> 9;
        src = (kq < 64u) ? x : h;
        row = mx * 128u + ch4 * 32u + r;
    } else {                             // B-chunks (Wx_g / Wh_g)
        const uint32_t V  = W - 16384u;
        kq = V & 127u;
        const uint32_t U  = V >> 7;      // ny*8 + b8
        const uint32_t b8 = U & 7u;
        const uint32_t ny = U >> 3;
        const uint32_t g  = b8 >> 1;
        const uint32_t nh = b8 & 1u;
        if (kq < 64u)
            src = (g == 0) ? Wxf : (g == 1) ? Wxi : (g == 2) ? Wxo : Wxc;
        else
            src = (g == 0) ? Whf : (g == 1) ? Whi : (g == 2) ? Who : Whc;
        row = ny * 64u + nh * 32u + r;
    }
    const float* s = src + (size_t)row * 1024u + (kq & 63u) * 16u + kh * 8u;
    const float4 v0 = *(const float4*)s;
    const float4 v1 = *(const float4*)(s + 4);
    short8 pk;
    pk[0] = (short)f2bf(v0.x); pk[1] = (short)f2bf(v0.y);
    pk[2] = (short)f2bf(v0.z); pk[3] = (short)f2bf(v0.w);
    pk[4] = (short)f2bf(v1.x); pk[5] = (short)f2bf(v1.y);
    pk[6] = (short)f2bf(v1.z); pk[7] = (short)f2bf(v1.w);
    *(short8*)(ws + (size_t)W * 512u + (uint32_t)l * 8u) = pk;
}

// ---------------------------------------------------------------------------
// Kernel 2: fused 4-gate GEMM + LSTM pointwise.  Round-0 skeleton (3-stage
// ring, 2 blocks/CU, ONE barrier + ONE vmcnt per K-step) with:
//  - 32x32x16 MFMA (2495 TF ceiling family vs 2075 for 16x16x32)
//  - ring unrolled x3 -> all LDS read addresses immediate-offset constants
//  - unified-KT packed source -> pure pointer-increment staging (no phase sel)
//  - RACE FIX: barrier drains lgkmcnt(0) too (pending ds_read vs DMA-overwrite
//    WAR on the stage ring), + sched_barrier(0) fence (rule #18).
// Tile: 128 rows x 4 gates x 64 cols, grid 512.  8 waves = 2M x 2N x 2G:
// wave = 64 rows x 32 cols x 2 gates; acc = 4 x floatx16 = 64 regs.
// Gate halves are exchanged through LDS (fp32) in the epilogue.
#define GLL(srcp, dstp) __builtin_amdgcn_global_load_lds(AS1(srcp), AS3(dstp), 16, 0, 0)
#define WAITB(N) do {                                                         \
    asm volatile("s_waitcnt vmcnt(" #N ") lgkmcnt(0)\ns_barrier" ::: "memory");\
    __builtin_amdgcn_sched_barrier(0);                                        \
} while (0)

#define MFMA32(a, b, c) __builtin_amdgcn_mfma_f32_32x32x16_bf16((a), (b), (c), 0, 0, 0)

#define ISSUE(SL) do {                                                        \
    GLL(p0, lds + (SL)*STAGE + loff0); p0 += ks0;                             \
    GLL(p1, lds + (SL)*STAGE + loff1); p1 += ks1;                             \
    GLL(p2, lds + (SL)*STAGE + loff2); p2 += ks2;                             \
} while (0)

#define COMPUTE(SC) do {                                                      \
    short8 a0_ = *(const short8*)(ldsA + (SC)*STAGE + 0);                     \
    short8 a1_ = *(const short8*)(ldsA + (SC)*STAGE + 1024);                  \
    short8 b0_ = *(const short8*)(ldsB + (SC)*STAGE + 0);                     \
    short8 b1_ = *(const short8*)(ldsB + (SC)*STAGE + 2048);                  \
    acc00 = MFMA32(a0_, b0_, acc00);                                          \
    acc01 = MFMA32(a1_, b0_, acc01);                                          \
    acc10 = MFMA32(a0_, b1_, acc10);                                          \
    acc11 = MFMA32(a1_, b1_, acc11);                                          \
    a0_ = *(const short8*)(ldsA + (SC)*STAGE + 4096);                         \
    a1_ = *(const short8*)(ldsA + (SC)*STAGE + 4096 + 1024);                  \
    b0_ = *(const short8*)(ldsB + (SC)*STAGE + 8192);                         \
    b1_ = *(const short8*)(ldsB + (SC)*STAGE + 8192 + 2048);                  \
    acc00 = MFMA32(a0_, b0_, acc00);                                          \
    acc01 = MFMA32(a1_, b0_, acc01);                                          \
    acc10 = MFMA32(a0_, b1_, acc10);                                          \
    acc11 = MFMA32(a1_, b1_, acc11);                                          \
} while (0)

#define ITER(SC, SL) do { WAITB(3); ISSUE(SL); COMPUTE(SC); } while (0)

__global__ __launch_bounds__(512, 4)
void lstm_fused_kernel(const unsigned short* __restrict__ ws,
                       const float* __restrict__ c,
                       const float* __restrict__ bxf, const float* __restrict__ bhf,
                       const float* __restrict__ bxi, const float* __restrict__ bhi,
                       const float* __restrict__ bxo, const float* __restrict__ bho,
                       const float* __restrict__ bxc, const float* __restrict__ bhc,
                       float* __restrict__ out)
{
    __shared__ __align__(16) char lds[3 * STAGE];   // 72 KB

    const int tid  = threadIdx.x;
    const int w    = tid >> 6;     // 0..7
    const int lane = tid & 63;

    // XCD-aware block swizzle (proven in round-0)
    const int bid = blockIdx.x;
    const int mx  = bid >> 4;                              // [0,32)
    const int ny  = ((bid & 7) << 1) | ((bid >> 3) & 1);   // [0,16)
    const int bm0 = mx * 128;
    const int bn0 = ny * 64;

    const int wM = w >> 2;         // M-half (64 rows)
    const int wN = (w >> 1) & 1;   // N-half (32 cols)
    const int gp = w & 1;          // gate pair: 0 -> {f,i}, 1 -> {o,c~}

    // staging: 24 chunks/stage; wave w DMAs ch = w*3 + i.
    // ch<8: A (kc=ch>>2, ch4=ch&3); ch>=8: B (b=ch-8, kc=b>>3, b8=b&7).
    // LDS stage layout: [A: kc*4096 + ch4*1024][B: 8192 + kc*8192 + b8*1024]
    //   == loff = ch*1024 uniformly.
    const unsigned short* p0; const unsigned short* p1; const unsigned short* p2;
    uint32_t loff0, loff1, loff2, ks0, ks1, ks2;
#define CHDEC(CH, P, LO, KS) do {                                             \
    const int ch_ = (CH);                                                     \
    if (ch_ < 8) {                                                            \
        const uint32_t kc_ = (uint32_t)ch_ >> 2, c4_ = (uint32_t)ch_ & 3u;    \
        P = ws + ((uint32_t)mx * 512u + kc_ * 4u + c4_) * 512u                \
               + (uint32_t)lane * 8u;                                         \
        KS = 4096u;                                                           \
    } else {                                                                  \
        const uint32_t b_ = (uint32_t)(ch_ - 8), kc_ = b_ >> 3, b8_ = b_ & 7u;\
        P = ws + (16384u + ((uint32_t)ny * 8u + b8_) * 128u + kc_) * 512u     \
               + (uint32_t)lane * 8u;                                         \
        KS = 1024u;                                                           \
    }                                                                         \
    LO = (uint32_t)ch_ * 1024u;                                               \
} while (0)
    CHDEC(w * 3 + 0, p0, loff0, ks0);
    CHDEC(w * 3 + 1, p1, loff1, ks1);
    CHDEC(w * 3 + 2, p2, loff2, ks2);
#undef CHDEC

    // fragment base pointers; all 24 ds_reads become base + immediate
    const char* ldsA = lds + (uint32_t)lane * 16u + (uint32_t)wM * 2048u;
    const char* ldsB = lds + (uint32_t)lane * 16u + 8192u
                           + ((uint32_t)(4 * gp + wN)) * 1024u;

    floatx16 acc00 = {0}, acc01 = {0}, acc10 = {0}, acc11 = {0}; // acc[gl][mt]

    // prologue: stages 0,1 in flight (6 outstanding/wave)
    ISSUE(0);
    ISSUE(1);

    // 64 K-steps; loads for kt land in stage kt%3; ITER(kt) computes kt%3,
    // issues kt+2 -> (kt+2)%3.  Unrolled x3 so stage offsets are constants.
    for (int t = 0; t < 20; ++t) {
        ITER(0, 2); ITER(1, 0); ITER(2, 1);     // kt = 3t, 3t+1, 3t+2
    }
    ITER(0, 2);                                 // kt = 60
    ITER(1, 0);                                 // kt = 61
    WAITB(3); COMPUTE(2);                       // kt = 62
    WAITB(0); COMPUTE(0);                       // kt = 63

    // ------------------------------------------------------------------ epi
    // acc[gl][mt]: gl = local gate (global g = 2*gp+gl), mt = 32-row tile.
    // C/D layout (32x32): col = lane&31, row = (r&3) + 8*(r>>2) + 4*(lane>>5)
    // Wave pair (w, w^1) shares rows/cols, complementary gate pairs.
    // Split: wave keeps mt = gp, writes mt = 1-gp grids to LDS (fp32, 64KB).
    const int colg = bn0 + (wN * 32) + (lane & 31);
    const int lq   = lane >> 5;
    const int wrow = wM * 64;
    float* out_ct = out;
    float* out_ht = out + (size_t)M_DIM * H_DIM;

    float bA, bB;
    if (gp == 0) { bA = bxf[colg] + bhf[colg]; bB = bxi[colg] + bhi[colg]; }
    else         { bA = bxo[colg] + bho[colg]; bB = bxc[colg] + bhc[colg]; }

    // activations in place (reg-only, before the barrier)
    if (gp == 0) {
#pragma unroll
        for (int r = 0; r < 16; ++r) {
            acc00[r] = fast_sigmoid(acc00[r] + bA);   // f, mt0
            acc01[r] = fast_sigmoid(acc01[r] + bA);   // f, mt1
            acc10[r] = fast_sigmoid(acc10[r] + bB);   // i, mt0
            acc11[r] = fast_sigmoid(acc11[r] + bB);   // i, mt1
        }
    } else {
#pragma unroll
        for (int r = 0; r < 16; ++r) {
            acc00[r] = fast_sigmoid(acc00[r] + bA);   // o, mt0
            acc01[r] = fast_sigmoid(acc01[r] + bA);   // o, mt1
            acc10[r] = fast_tanh(acc10[r] + bB);      // c~, mt0
            acc11[r] = fast_tanh(acc11[r] + bB);      // c~, mt1
        }
    }

    __syncthreads();   // all stage reads done before exchange overwrites LDS

    // write the NON-kept tile (mt = 1-gp), both gates:
    // region: pair*16KB + gp*8KB + gl*4KB + row*128 + col*4
    {
        char* wr = (char*)lds + (uint32_t)(w >> 1) * 16384u + (uint32_t)gp * 8192u;
        if (gp == 0) {
#pragma unroll
            for (int r = 0; r < 16; ++r) {
                const int ri = (r & 3) + 8 * (r >> 2) + 4 * lq;
                *(float*)(wr +        ri * 128 + (lane & 31) * 4) = acc01[r]; // f(mt1)
                *(float*)(wr + 4096 + ri * 128 + (lane & 31) * 4) = acc11[r]; // i(mt1)
            }
        } else {
#pragma unroll
            for (int r = 0; r < 16; ++r) {
                const int ri = (r & 3) + 8 * (r >> 2) + 4 * lq;
                *(float*)(wr +        ri * 128 + (lane & 31) * 4) = acc00[r]; // o(mt0)
                *(float*)(wr + 4096 + ri * 128 + (lane & 31) * 4) = acc10[r]; // c~(mt0)
            }
        }
    }

    __syncthreads();

    // read partner's grids for the kept tile, fuse, store
    {
        const char* rd = (const char*)lds + (uint32_t)(w >> 1) * 16384u
                                          + (uint32_t)(1 - gp) * 8192u;
        if (gp == 0) {     // kept mt0: own F=acc00, I=acc10; partner O, CT
#pragma unroll
            for (int r = 0; r < 16; ++r) {
                const int ri = (r & 3) + 8 * (r >> 2) + 4 * lq;
                const float O  = *(const float*)(rd +        ri * 128 + (lane & 31) * 4);
                const float CT = *(const float*)(rd + 4096 + ri * 128 + (lane & 31) * 4);
                const int row = bm0 + wrow + ri;
                const float cv  = c[(size_t)row * H_DIM + colg];
                const float ctn = acc00[r] * cv + CT * acc10[r];
                const float htn = fast_tanh(ctn) * O;
                out_ct[(size_t)row * H_DIM + colg] = ctn;
                out_ht[(size_t)row * H_DIM + colg] = htn;
            }
        } else {           // kept mt1: own O=acc01, CT=acc11; partner F, I
#pragma unroll
            for (int r = 0; r < 16; ++r) {
                const int ri = (r & 3) + 8 * (r >> 2) + 4 * lq;
                const float F = *(const float*)(rd +        ri * 128 + (lane & 31) * 4);
                const float I = *(const float*)(rd + 4096 + ri * 128 + (lane & 31) * 4);
                const int row = bm0 + wrow + 32 + ri;
                const float cv  = c[(size_t)row * H_DIM + colg];
                const float ctn = F * cv + acc11[r] * I;
                const float htn = fast_tanh(ctn) * acc01[r];
                out_ct[(size_t)row * H_DIM + colg] = ctn;
                out_ht[(size_t)row * H_DIM + colg] = htn;
            }
        }
    }
}

extern "C" void kernel_launch(void* const* d_in, const int* in_sizes, int n_in,
                              void* d_out, int out_size, void* d_ws, size_t ws_size,
                              hipStream_t stream) {
    (void)in_sizes; (void)n_in; (void)out_size; (void)ws_size;
    const float* x   = (const float*)d_in[0];
    const float* c   = (const float*)d_in[1];
    const float* h   = (const float*)d_in[2];
    const float* Wxf = (const float*)d_in[3];  const float* bxf = (const float*)d_in[4];
    const float* Whf = (const float*)d_in[5];  const float* bhf = (const float*)d_in[6];
    const float* Wxi = (const float*)d_in[7];  const float* bxi = (const float*)d_in[8];
    const float* Whi = (const float*)d_in[9];  const float* bhi = (const float*)d_in[10];
    const float* Wxo = (const float*)d_in[11]; const float* bxo = (const float*)d_in[12];
    const float* Who = (const float*)d_in[13]; const float* bho = (const float*)d_in[14];
    const float* Wxc = (const float*)d_in[15]; const float* bxc = (const float*)d_in[16];
    const float* Whc = (const float*)d_in[17]; const float* bhc = (const float*)d_in[18];
    float* out = (float*)d_out;
    unsigned short* ws = (unsigned short*)d_ws;   // 32768 chunks x 1 KB = 32 MB

    pack_bf16<<<8192, 256, 0, stream>>>(x, h,
        Wxf, Wxi, Wxo, Wxc, Whf, Whi, Who, Whc, ws);

    lstm_fused_kernel<<<512, 512, 0, stream>>>(ws, c,
        bxf, bhf, bxi, bhi, bxo, bho, bxc, bhc, out);
}

// Round 5
// 228.287 us; speedup vs baseline: 1.0840x; 1.0840x over previous
//
#include <hip/hip_runtime.h>
#include <hip/hip_bf16.h>
#include <stdint.h>

typedef __hip_bfloat16 bf16;
typedef __attribute__((ext_vector_type(8))) short short8;    // 8 bf16 = 4 VGPRs (MFMA A/B frag)
typedef __attribute__((ext_vector_type(16))) float floatx16; // 32x32 MFMA C/D frag

#define AS1(p) ((const __attribute__((address_space(1))) void*)(p))
#define AS3(p) ((__attribute__((address_space(3))) void*)(p))

#define M_DIM 4096
#define H_DIM 1024
#define STAGE 24576          // A 8KB + B 16KB per K-step(32); 3 stages = 72KB -> 2 blocks/CU

// fp32 -> bf16 bits, round-to-nearest-even (inputs are finite)
__device__ __forceinline__ unsigned short f2bf(float f) {
    uint32_t u = __float_as_uint(f);
    uint32_t r = (u + 0x7FFFu + ((u >> 16) & 1u)) >> 16;
    return (unsigned short)r;
}
__device__ __forceinline__ float fast_sigmoid(float v) {
    return 1.0f / (1.0f + __expf(-v));
}
__device__ __forceinline__ float fast_tanh(float v) {
    return 2.0f / (1.0f + __expf(-2.0f * v)) - 1.0f;
}

// ---------------------------------------------------------------------------
// Kernel 1: PACK fp32 -> bf16 chunks, lane-LINEAR (no swizzle: the 32x32x16
// fragment order IS linear lane order).  One chunk = 1 KB = [2 kh][32 rows]
// [8 bf16] = the exact A/B fragment for one 32-row x 16-k tile; lane l reads
// bytes l*16 of the chunk.
// Unified KT: kq in [0,128) spans x-K (kq<64) then h-K (kq>=64), so the GEMM
// walks K with one uniform pointer increment (no phase select).
// Chunk map (32768 chunks x 1KB = 32MB):
//   A (W<16384):  W = (mx*128 + kq)*4 + ch4 ; mx<32 (128-row panel),
//                 ch4<4 (32-row group) ; row = mx*128+ch4*32+r
//   B (W>=16384): W-16384 = (ny*8 + b8)*128 + kq ; ny<16 (64-col panel),
//                 b8 = g*2+nh (gate, 32-col half) ; row = ny*64+nh*32+r
__global__ __launch_bounds__(256)
void pack_bf16(const float* __restrict__ x, const float* __restrict__ h,
               const float* Wxf, const float* Wxi, const float* Wxo, const float* Wxc,
               const float* Whf, const float* Whi, const float* Who, const float* Whc,
               unsigned short* __restrict__ ws)
{
    const int w = threadIdx.x >> 6;
    const int l = threadIdx.x & 63;
    const uint32_t W = blockIdx.x * 4u + (uint32_t)w;   // chunk id [0, 32768)

    const uint32_t r  = (uint32_t)l & 31u;   // row in chunk
    const uint32_t kh = (uint32_t)l >> 5;    // k-subgroup of 8

    const float* src;
    uint32_t row, kq;
    if (W < 16384u) {                    // A-chunks (x / h)
        const uint32_t ch4 = W & 3u;
        kq = (W >> 2) & 127u;
        const uint32_t mx = W >> 9;
        src = (kq < 64u) ? x : h;
        row = mx * 128u + ch4 * 32u + r;
    } else {                             // B-chunks (Wx_g / Wh_g)
        const uint32_t V  = W - 16384u;
        kq = V & 127u;
        const uint32_t U  = V >> 7;      // ny*8 + b8
        const uint32_t b8 = U & 7u;
        const uint32_t ny = U >> 3;
        const uint32_t g  = b8 >> 1;
        const uint32_t nh = b8 & 1u;
        if (kq < 64u)
            src = (g == 0) ? Wxf : (g == 1) ? Wxi : (g == 2) ? Wxo : Wxc;
        else
            src = (g == 0) ? Whf : (g == 1) ? Whi : (g == 2) ? Who : Whc;
        row = ny * 64u + nh * 32u + r;
    }
    const float* s = src + (size_t)row * 1024u + (kq & 63u) * 16u + kh * 8u;
    const float4 v0 = *(const float4*)s;
    const float4 v1 = *(const float4*)(s + 4);
    short8 pk;
    pk[0] = (short)f2bf(v0.x); pk[1] = (short)f2bf(v0.y);
    pk[2] = (short)f2bf(v0.z); pk[3] = (short)f2bf(v0.w);
    pk[4] = (short)f2bf(v1.x); pk[5] = (short)f2bf(v1.y);
    pk[6] = (short)f2bf(v1.z); pk[7] = (short)f2bf(v1.w);
    *(short8*)(ws + (size_t)W * 512u + (uint32_t)l * 8u) = pk;
}

// ---------------------------------------------------------------------------
// Kernel 2: fused 4-gate GEMM + LSTM pointwise.  Round-0 skeleton (3-stage
// ring, 2 blocks/CU, ONE barrier + ONE vmcnt per K-step) with:
//  - 32x32x16 MFMA
//  - EXCHANGE-FREE wave mapping: wave = 32 rows x 32 cols x ALL 4 gates
//    (8 waves = 4M x 2N).  acc[4] = 64 regs; epilogue fully wave-local ->
//    no LDS exchange, no spill (round-4's 54 MB scratch traffic).
//  - ring unrolled x3 -> all LDS read addresses immediate-offset constants
//  - unified-KT packed source -> pure pointer-increment staging
//  - barrier drains lgkmcnt(0) (stage-ring WAR fix) + sched_barrier(0) fence
#define GLL(srcp, dstp) __builtin_amdgcn_global_load_lds(AS1(srcp), AS3(dstp), 16, 0, 0)
#define WAITB(N) do {                                                         \
    asm volatile("s_waitcnt vmcnt(" #N ") lgkmcnt(0)\ns_barrier" ::: "memory");\
    __builtin_amdgcn_sched_barrier(0);                                        \
} while (0)

#define MFMA32(a, b, c) __builtin_amdgcn_mfma_f32_32x32x16_bf16((a), (b), (c), 0, 0, 0)

#define ISSUE(SL) do {                                                        \
    GLL(p0, lds + (SL)*STAGE + loff0); p0 += ks0;                             \
    GLL(p1, lds + (SL)*STAGE + loff1); p1 += ks1;                             \
    GLL(p2, lds + (SL)*STAGE + loff2); p2 += ks2;                             \
} while (0)

#define COMPUTE(SC) do {                                                      \
    short8 a_  = *(const short8*)(ldsA + (SC)*STAGE + 0);                     \
    short8 b0_ = *(const short8*)(ldsB + (SC)*STAGE + 0);                     \
    short8 b1_ = *(const short8*)(ldsB + (SC)*STAGE + 2048);                  \
    short8 b2_ = *(const short8*)(ldsB + (SC)*STAGE + 4096);                  \
    short8 b3_ = *(const short8*)(ldsB + (SC)*STAGE + 6144);                  \
    acc0 = MFMA32(a_, b0_, acc0);                                             \
    acc1 = MFMA32(a_, b1_, acc1);                                             \
    acc2 = MFMA32(a_, b2_, acc2);                                             \
    acc3 = MFMA32(a_, b3_, acc3);                                             \
    a_  = *(const short8*)(ldsA + (SC)*STAGE + 4096);                         \
    b0_ = *(const short8*)(ldsB + (SC)*STAGE + 8192);                         \
    b1_ = *(const short8*)(ldsB + (SC)*STAGE + 8192 + 2048);                  \
    b2_ = *(const short8*)(ldsB + (SC)*STAGE + 8192 + 4096);                  \
    b3_ = *(const short8*)(ldsB + (SC)*STAGE + 8192 + 6144);                  \
    acc0 = MFMA32(a_, b0_, acc0);                                             \
    acc1 = MFMA32(a_, b1_, acc1);                                             \
    acc2 = MFMA32(a_, b2_, acc2);                                             \
    acc3 = MFMA32(a_, b3_, acc3);                                             \
} while (0)

#define ITER(SC, SL) do { WAITB(3); ISSUE(SL); COMPUTE(SC); } while (0)

__global__ __launch_bounds__(512, 4)
void lstm_fused_kernel(const unsigned short* __restrict__ ws,
                       const float* __restrict__ c,
                       const float* __restrict__ bxf, const float* __restrict__ bhf,
                       const float* __restrict__ bxi, const float* __restrict__ bhi,
                       const float* __restrict__ bxo, const float* __restrict__ bho,
                       const float* __restrict__ bxc, const float* __restrict__ bhc,
                       float* __restrict__ out)
{
    __shared__ __align__(16) char lds[3 * STAGE];   // 72 KB

    const int tid  = threadIdx.x;
    const int w    = tid >> 6;     // 0..7
    const int lane = tid & 63;

    // XCD-aware block swizzle (proven in round-0)
    const int bid = blockIdx.x;
    const int mx  = bid >> 4;                              // [0,32)
    const int ny  = ((bid & 7) << 1) | ((bid >> 3) & 1);   // [0,16)
    const int bm0 = mx * 128;
    const int bn0 = ny * 64;

    const int wM2 = w >> 1;        // 32-row group [0,4)
    const int wN  = w & 1;         // 32-col half  [0,2)

    // staging: 24 chunks/stage; wave w DMAs ch = w*3 + i (independent of
    // the compute mapping).  ch<8: A (kc=ch>>2, ch4=ch&3); ch>=8: B
    // (b=ch-8, kc=b>>3, b8=b&7).
    // LDS stage layout: [A: kc*4096 + ch4*1024][B: 8192 + kc*8192 + b8*1024]
    //   == loff = ch*1024 uniformly.
    const unsigned short* p0; const unsigned short* p1; const unsigned short* p2;
    uint32_t loff0, loff1, loff2, ks0, ks1, ks2;
#define CHDEC(CH, P, LO, KS) do {                                             \
    const int ch_ = (CH);                                                     \
    if (ch_ < 8) {                                                            \
        const uint32_t kc_ = (uint32_t)ch_ >> 2, c4_ = (uint32_t)ch_ & 3u;    \
        P = ws + ((uint32_t)mx * 512u + kc_ * 4u + c4_) * 512u                \
               + (uint32_t)lane * 8u;                                         \
        KS = 4096u;                                                           \
    } else {                                                                  \
        const uint32_t b_ = (uint32_t)(ch_ - 8), kc_ = b_ >> 3, b8_ = b_ & 7u;\
        P = ws + (16384u + ((uint32_t)ny * 8u + b8_) * 128u + kc_) * 512u     \
               + (uint32_t)lane * 8u;                                         \
        KS = 1024u;                                                           \
    }                                                                         \
    LO = (uint32_t)ch_ * 1024u;                                               \
} while (0)
    CHDEC(w * 3 + 0, p0, loff0, ks0);
    CHDEC(w * 3 + 1, p1, loff1, ks1);
    CHDEC(w * 3 + 2, p2, loff2, ks2);
#undef CHDEC

    // fragment base pointers; all LDS reads are base + immediate offset
    const char* ldsA = lds + (uint32_t)lane * 16u + (uint32_t)wM2 * 1024u;
    const char* ldsB = lds + (uint32_t)lane * 16u + 8192u + (uint32_t)wN * 1024u;

    floatx16 acc0 = {0}, acc1 = {0}, acc2 = {0}, acc3 = {0};  // gates f,i,o,c~

    // prologue: stages 0,1 in flight (6 outstanding/wave)
    ISSUE(0);
    ISSUE(1);

    // 64 K-steps; loads for kt land in stage kt%3; ITER(kt) computes kt%3,
    // issues kt+2 -> (kt+2)%3.  Unrolled x3 so stage offsets are constants.
    for (int t = 0; t < 20; ++t) {
        ITER(0, 2); ITER(1, 0); ITER(2, 1);     // kt = 3t, 3t+1, 3t+2
    }
    ITER(0, 2);                                 // kt = 60
    ITER(1, 0);                                 // kt = 61
    WAITB(3); COMPUTE(2);                       // kt = 62
    WAITB(0); COMPUTE(0);                       // kt = 63

    // ------------------------------------------------------------------ epi
    // All 4 gates wave-local.  C/D layout (32x32):
    //   col = lane&31, row = (r&3) + 8*(r>>2) + 4*(lane>>5)
    const int colg = bn0 + wN * 32 + (lane & 31);
    const int lq   = lane >> 5;
    const int row0 = bm0 + wM2 * 32;
    float* out_ct = out;
    float* out_ht = out + (size_t)M_DIM * H_DIM;

    const float bf_ = bxf[colg] + bhf[colg];
    const float bi_ = bxi[colg] + bhi[colg];
    const float bo_ = bxo[colg] + bho[colg];
    const float bc_ = bxc[colg] + bhc[colg];

#pragma unroll
    for (int r = 0; r < 16; ++r) {
        const int ri  = (r & 3) + 8 * (r >> 2) + 4 * lq;
        const int row = row0 + ri;
        const float f    = fast_sigmoid(acc0[r] + bf_);
        const float ii   = fast_sigmoid(acc1[r] + bi_);
        const float o    = fast_sigmoid(acc2[r] + bo_);
        const float ctil = fast_tanh(acc3[r] + bc_);
        const float cv   = c[(size_t)row * H_DIM + colg];
        const float ctn  = f * cv + ctil * ii;
        const float htn  = fast_tanh(ctn) * o;
        out_ct[(size_t)row * H_DIM + colg] = ctn;
        out_ht[(size_t)row * H_DIM + colg] = htn;
    }
}

extern "C" void kernel_launch(void* const* d_in, const int* in_sizes, int n_in,
                              void* d_out, int out_size, void* d_ws, size_t ws_size,
                              hipStream_t stream) {
    (void)in_sizes; (void)n_in; (void)out_size; (void)ws_size;
    const float* x   = (const float*)d_in[0];
    const float* c   = (const float*)d_in[1];
    const float* h   = (const float*)d_in[2];
    const float* Wxf = (const float*)d_in[3];  const float* bxf = (const float*)d_in[4];
    const float* Whf = (const float*)d_in[5];  const float* bhf = (const float*)d_in[6];
    const float* Wxi = (const float*)d_in[7];  const float* bxi = (const float*)d_in[8];
    const float* Whi = (const float*)d_in[9];  const float* bhi = (const float*)d_in[10];
    const float* Wxo = (const float*)d_in[11]; const float* bxo = (const float*)d_in[12];
    const float* Who = (const float*)d_in[13]; const float* bho = (const float*)d_in[14];
    const float* Wxc = (const float*)d_in[15]; const float* bxc = (const float*)d_in[16];
    const float* Whc = (const float*)d_in[17]; const float* bhc = (const float*)d_in[18];
    float* out = (float*)d_out;
    unsigned short* ws = (unsigned short*)d_ws;   // 32768 chunks x 1 KB = 32 MB

    pack_bf16<<<8192, 256, 0, stream>>>(x, h,
        Wxf, Wxi, Wxo, Wxc, Whf, Whi, Who, Whc, ws);

    lstm_fused_kernel<<<512, 512, 0, stream>>>(ws, c,
        bxf, bhf, bxi, bhi, bxo, bho, bxc, bhc, out);
}